// Round 7
// baseline (373.555 us; speedup 1.0000x reference)
//
#include <hip/hip_runtime.h>
#include <type_traits>
#include <utility>

#define DI __device__ __forceinline__

typedef unsigned short u16;
typedef float f32x4 __attribute__((ext_vector_type(4)));
typedef float f32x16 __attribute__((ext_vector_type(16)));
typedef short s16x8 __attribute__((ext_vector_type(8)));
typedef __bf16 bf16x8 __attribute__((ext_vector_type(8)));

// ---- pick whichever vector type the gfx950 bf16 MFMA builtin accepts ----
template <typename V, typename = void>
struct mfma_ok : std::false_type {};
template <typename V>
struct mfma_ok<V, std::void_t<decltype(__builtin_amdgcn_mfma_f32_16x16x32_bf16(
    std::declval<V>(), std::declval<V>(), std::declval<f32x4>(), 0, 0, 0))>>
    : std::true_type {};
using frag_t = std::conditional_t<mfma_ok<bf16x8>::value, bf16x8, s16x8>;

union U128 {
  int4 i;
  frag_t f;
  u16 s[8];
};

DI f32x4 mfma16(const U128& a, const U128& b, f32x4 c) {
  return __builtin_amdgcn_mfma_f32_16x16x32_bf16(a.f, b.f, c, 0, 0, 0);
}
DI f32x16 mfma32(const U128& a, const U128& b, f32x16 c) {
  return __builtin_amdgcn_mfma_f32_32x32x16_bf16(a.f, b.f, c, 0, 0, 0);
}

DI u16 f2b(float x) {  // fp32 -> bf16 RNE (finite inputs)
  union { float f; unsigned u; } v; v.f = x;
  unsigned r = v.u + 0x7FFFu + ((v.u >> 16) & 1u);
  return (u16)(r >> 16);
}

// Packed fp32 pair -> bf16x2 in one u32 (compiler emits v_cvt_pk_bf16_f32).
DI unsigned pk2bf(float a, float b) {
  unsigned short ua = __builtin_bit_cast(unsigned short, (__bf16)a);
  unsigned short ub = __builtin_bit_cast(unsigned short, (__bf16)b);
  return (unsigned)ua | ((unsigned)ub << 16);
}

#if __has_builtin(__builtin_amdgcn_exp2f)
#define EXP2F __builtin_amdgcn_exp2f
#else
#define EXP2F exp2f
#endif

// v_permlane32_swap_b32 via inline asm.
// After: lo = {h0: own lo | h1: partner hi}, hi = {h0: partner lo | h1: own hi}
DI void plswap(unsigned& lo, unsigned& hi) {
  asm("v_permlane32_swap_b32 %0, %1" : "+v"(lo), "+v"(hi));
}

typedef __attribute__((address_space(1))) void gas_t;
typedef __attribute__((address_space(3))) void las_t;
DI void gll16(const void* g, void* l) {  // async global->LDS, 16B/lane
  __builtin_amdgcn_global_load_lds((gas_t*)g, (las_t*)l, 16, 0, 0);
}

// cs * log2(e): folded into Q at GEMM1 routing so flash uses exp2 directly.
#define QSCALE 0.12751791437603762f  /* (1/sqrt(128)) * 1.4426950408889634 */

// ---- shared 64x64 fp32->bf16 transpose tile (used by k_pre and k_flash tail) ----
DI void transpose_tile(const float* __restrict__ in, u16* __restrict__ out,
                       int R, int C, int bx, int by, int t, u16 (*Tb)[68]) {
  long r0 = (long)by * 64, c0 = (long)bx * 64;
  int cq = (t & 15) * 4, rr = t >> 4;
#pragma unroll
  for (int it = 0; it < 4; ++it) {
    int r = rr + it * 16;
    float4 v = *(const float4*)(in + (r0 + r) * C + c0 + cq);
    Tb[r][cq + 0] = f2b(v.x); Tb[r][cq + 1] = f2b(v.y);
    Tb[r][cq + 2] = f2b(v.z); Tb[r][cq + 3] = f2b(v.w);
  }
  __syncthreads();
#pragma unroll
  for (int it = 0; it < 2; ++it) {
    int ci = it * 256 + t;
    int cc = ci >> 3, ch = ci & 7, rb = ch * 8;
    unsigned p0 = Tb[rb + 0][cc] | ((unsigned)Tb[rb + 1][cc] << 16);
    unsigned p1 = Tb[rb + 2][cc] | ((unsigned)Tb[rb + 3][cc] << 16);
    unsigned p2 = Tb[rb + 4][cc] | ((unsigned)Tb[rb + 5][cc] << 16);
    unsigned p3 = Tb[rb + 6][cc] | ((unsigned)Tb[rb + 7][cc] << 16);
    *(int4*)(out + (c0 + cc) * R + r0 + rb) = make_int4(p0, p1, p2, p3);
  }
}

// ---------------- fused preprocessing: x->bf16 + Wqkv transpose ----------------
// blocks [0,8192): conv of x (8192*256 float4s exactly)
// blocks [8192,11264): Wqkv [2048][6144] -> wqkvt [6144][2048] (96x32 tiles)
__global__ __launch_bounds__(256) void k_pre(const float* __restrict__ x,
                                             u16* __restrict__ xb,
                                             const float* __restrict__ Wqkv,
                                             u16* __restrict__ wqkvt) {
  __shared__ __attribute__((aligned(16))) u16 Tb[64][68];
  int bid = blockIdx.x, t = threadIdx.x;
  if (bid < 8192) {
    int i = bid * 256 + t;
    float4 v = ((const float4*)x)[i];
    ushort4 o;
    o.x = f2b(v.x); o.y = f2b(v.y); o.z = f2b(v.z); o.w = f2b(v.w);
    ((ushort4*)xb)[i] = o;
    return;
  }
  int idx = bid - 8192;  // [0, 3072) = 96 x 32 tiles
  transpose_tile(Wqkv, wqkvt, 2048, 6144, idx % 96, idx / 96, t, Tb);
}

// ---------------- C[M][N] = A[M][K] * Bt[N][K]^T + bias (128x128 tile) ----------------
// BK=64, XOR chunk swizzle (conflict-free on the GEMM phase).
// Proven 986 TF @ GEMM1 shape via ~2.7 blocks/CU TLP (m97-family structure).
// MODE 0: fp32 packed-pair out to Cout (GEMM2).
// MODE 1: bf16 routed out (GEMM1): per-128-col group -> q/k of head grp/3;
//         V groups (rsel==2) transposed through LDS and written DIRECTLY in the
//         TILED vt layout [bh][stile][d][s%128] -> block-contiguous 32KB,
//         fully coalesced stores (round-6 fix: old d-major mapping was a
//         stride-4KB scatter -> +7us and 262K bank conflicts).
template <int MODE>
__global__ __launch_bounds__(256, 4) void k_gemm_bt(const u16* __restrict__ A,
                                                    const u16* __restrict__ Bt,
                                                    const float* __restrict__ bias,
                                                    void* __restrict__ Cout,
                                                    u16* __restrict__ qb,
                                                    u16* __restrict__ kbv,
                                                    u16* __restrict__ vt,
                                                    int n_off,
                                                    int M, int N, int K) {
  // SM: As=[0,8192) u16, Bs=[8192,16384). V-epilogue reuses SM as a d-major
  // padded [128][130] tile (16640 u16 = 33280 B).
  __shared__ __attribute__((aligned(16))) u16 SM[16640];
  u16* As = SM;
  u16* Bs = SM + 8192;
  int t = threadIdx.x;
  int lane = t & 63, w = t >> 6, quad = lane >> 4, l15 = lane & 15;
  long m0 = (long)blockIdx.y * 128, n0 = n_off + (long)blockIdx.x * 128;
  int wr = (w >> 1) * 64, wc = (w & 1) * 64;
  int sw = l15 & 7;
  f32x4 acc[4][4] = {};
  for (int k0 = 0; k0 < K; k0 += 64) {
    __syncthreads();
#pragma unroll
    for (int it = 0; it < 4; ++it) {
      int ci = it * 256 + t;
      int row = ci >> 3, cl = (ci & 7) ^ (row & 7);
      gll16(A + (m0 + row) * K + k0 + cl * 8, As + ci * 8);
      gll16(Bt + (n0 + row) * K + k0 + cl * 8, Bs + ci * 8);
    }
    __syncthreads();
#pragma unroll
    for (int kk = 0; kk < 2; ++kk) {
      U128 a[4], b[4];
#pragma unroll
      for (int i = 0; i < 4; ++i)
        a[i].i = *(const int4*)(As + (wr + i * 16 + l15) * 64 + (((kk * 4 + quad) ^ sw) << 3));
#pragma unroll
      for (int j = 0; j < 4; ++j)
        b[j].i = *(const int4*)(Bs + (wc + j * 16 + l15) * 64 + (((kk * 4 + quad) ^ sw) << 3));
#pragma unroll
      for (int i = 0; i < 4; ++i)
#pragma unroll
        for (int j = 0; j < 4; ++j)
          acc[i][j] = mfma16(a[i], b[j], acc[i][j]);
    }
  }
  float bj[4];
#pragma unroll
  for (int j = 0; j < 4; ++j) bj[j] = bias[n0 + wc + j * 16 + l15];

  // routing (block-uniform: n0 block-uniform, wc<128 so grp = n0>>7)
  int hidx = (int)(n0 / 384);
  int rsel = (int)(n0 - hidx * 384) >> 7;  // 0=Q 1=K 2=V

  if (MODE == 1 && rsel == 2) {
    // ---- V^T direct write through LDS, tiled-coalesced ----
    __syncthreads();  // all waves done reading As/Bs (SM reused as [128][130])
#pragma unroll
    for (int i = 0; i < 4; ++i)
#pragma unroll
      for (int rr2 = 0; rr2 < 4; ++rr2) {
        int m = wr + i * 16 + quad * 4 + rr2;  // s within tile
#pragma unroll
        for (int j = 0; j < 4; ++j)
          SM[(wc + j * 16 + l15) * 130 + m] = f2b(acc[i][j][rr2] + bj[j]);
      }
    __syncthreads();
    int bidx = (int)(m0 >> 11);
    int stile = (int)((m0 & 2047) >> 7);
    u16* vtile = vt + (long)(bidx * 16 + hidx) * 262144 + stile * 16384;
    const unsigned* sm32 = (const unsigned*)SM;
#pragma unroll
    for (int it = 0; it < 8; ++it) {
      int ci = it * 256 + t;               // [0,2048)
      int d = ci >> 4, sb = (ci & 15) * 8; // lanes: consecutive s -> coalesced
      int base = (d * 130 + sb) >> 1;      // dword-aligned (130,sb even)
      *(int4*)(vtile + d * 128 + sb) =
          make_int4(sm32[base], sm32[base + 1], sm32[base + 2], sm32[base + 3]);
    }
    return;
  }

  u16* route = (MODE == 1) ? (rsel == 0 ? qb : kbv) : nullptr;

#pragma unroll
  for (int i = 0; i < 4; ++i) {
#pragma unroll
    for (int rr2 = 0; rr2 < 4; ++rr2) {
      long row = m0 + wr + i * 16 + quad * 4 + rr2;
#pragma unroll
      for (int j = 0; j < 4; ++j) {
        float v = acc[i][j][rr2] + bj[j];
        if (MODE == 1) {
          if (rsel == 0) v *= QSCALE;  // pre-scale Q (block-uniform branch)
          int bidx = (int)(row >> 11), s = (int)(row & 2047);
          long obase = ((long)(bidx * 16 + hidx) * 2048 + s) * 128;
          int dh = wc + j * 16 + l15;
          unsigned pb = f2b(v);
          unsigned other = __shfl_xor(pb, 1);
          if (!(l15 & 1))
            ((unsigned*)route)[(obase + dh) >> 1] = pb | (other << 16);
        } else {
          long col = n0 + wc + j * 16 + l15;
          unsigned bits = __float_as_uint(v);
          unsigned other = __shfl_xor(bits, 1);
          if (!(l15 & 1)) {
            uint2 pr; pr.x = bits; pr.y = other;
            *(uint2*)((float*)Cout + row * N + col) = pr;
          }
        }
      }
    }
  }
}

// ---------------- flash attention: 32x32x16, S^T, dbuf + counted vmcnt ----------------
// Round-6: 8 waves/block (512 thr), 256 q-rows/block, grid (8,96).
//   - 2 blocks/CU (64KB LDS) -> 16 waves/CU (occupancy 20%->~50%)
//   - K/V staged once per 256 q (total staging traffic halves)
//   - stage = 4 gll16/thread -> counted wait is vmcnt(4)
// Intra-tile interleave: QK0+QK1 -> SM0 -> PV0 -> SM1a -> PV1 -> SM1b -> PV2+PV3.
// 4-way lsum partials; XOR-merged per-lane LDS read bases (1 v_xor per ds_read).
// by>=32: Wout-transpose tail blocks, 2 tiles per 512-thread block (woutt
// overlaps wqkvt which is dead after GEMM1).
__global__ __launch_bounds__(512, 2) void k_flash(const u16* __restrict__ qb,
                                                  const u16* __restrict__ kb,
                                                  const u16* __restrict__ vt,
                                                  u16* __restrict__ attn,
                                                  const float* __restrict__ Wout,
                                                  u16* __restrict__ woutt) {
  __shared__ __attribute__((aligned(16))) u16 Ks[2][64 * 128];   // [key][dh], chunk-swizzled
  __shared__ __attribute__((aligned(16))) u16 Vts[2][128 * 64];  // [dh][key], chunk-swizzled
  if (blockIdx.y >= 32) {  // fused Wout transpose tail (2 tiles per block)
    int half = threadIdx.x >> 8, tt = threadIdx.x & 255;
    u16 (*Tb)[68] = (u16(*)[68])(&Ks[0][0] + half * 64 * 68);
    int u = ((blockIdx.y - 32) * 8 + blockIdx.x) * 2 + half;  // [0, 1024)
    transpose_tile(Wout, woutt, 2048, 2048, u & 31, u >> 5, tt, Tb);
    return;
  }
  int t = threadIdx.x;
  int lane = t & 63, w = t >> 6, l31 = lane & 31, h = lane >> 5;
  int q0 = blockIdx.x * 256 + w * 32;
  int bh = blockIdx.y, b = bh >> 4, hd = bh & 15;

  // Q B-frags from contiguous qb: lane holds Q[q0+l31][dht*16 + h*8 + j]
  const u16* qbase = qb + ((long)bh * 2048 + q0 + l31) * 128;
  U128 qf[8];
#pragma unroll
  for (int dht = 0; dht < 8; ++dht)
    qf[dht].i = *(const int4*)(qbase + dht * 16 + h * 8);
  // Drain Q loads so no q-load vmcnt dependency is carried into the loop.
  __syncthreads();

  f32x16 O[4] = {};  // O^T: col=q, rows=dh (4 blocks of 32)
  float ls0 = 0.f, ls1 = 0.f, ls2 = 0.f, ls3 = 0.f;
  const u16* kbh = kb + (long)bh * 2048 * 128;
  long vbase = (long)bh * 262144;  // tiled vt: [bh][stile][d][s%128]

  // Merged per-lane LDS read bases (u16 units). Verified algebra:
  //  K:  row*128 + ((dht*2+h)^(row&7))*8  ==  kinv ^ (dht<<4)  (+4096 for kb2=1)
  //      kinv = l31<<7 ^ ((l31&7)<<3) ^ (h<<3)
  //  V:  vrow*64 + ((kt*2+h)^(vrow&7))*8 ==  vinv ^ (kt<<4)  (+dht*2048)
  //      vinv = l31<<6 ^ ((l31&7)<<3) ^ (h<<3)
  unsigned swx = (unsigned)(((l31 & 7) << 3) ^ (h << 3));
  unsigned kinv = ((unsigned)l31 << 7) ^ swx;
  unsigned vinv = ((unsigned)l31 << 6) ^ swx;

  // stage one 64-key tile: 4 gll16/thread (2 K rows + 2 V^T rows) @512 threads
  auto stage = [&](int buf, int k0) {
#pragma unroll
    for (int it = 0; it < 2; ++it) {  // K tile: 64 keys x 128 dh
      int ci = it * 512 + t;
      int key = ci >> 4, cp = ci & 15, cl = cp ^ (key & 7);
      gll16(kbh + (long)(k0 + key) * 128 + cl * 8, &Ks[buf][0] + ci * 8);
    }
#pragma unroll
    for (int it = 0; it < 2; ++it) {  // V^T tile: 128 dh x 64 keys (tiled vt)
      int ci = it * 512 + t;
      int d = ci >> 3, cp = ci & 7, cl = cp ^ (d & 7);
      gll16(vt + vbase + ((k0 >> 7) << 14) + d * 128 + (k0 & 64) + cl * 8,
            &Vts[buf][0] + ci * 8);
    }
  };

  stage(0, 0);
  int cur = 0;
  for (int k0 = 0; k0 < 2048; k0 += 64) {
    if (k0 + 64 < 2048) {
      stage(cur ^ 1, k0 + 64);                          // prefetch next tile
      asm volatile("s_waitcnt vmcnt(4)" ::: "memory");  // current tile landed
    } else {
      asm volatile("s_waitcnt vmcnt(0)" ::: "memory");  // last tile: drain
    }
    __builtin_amdgcn_s_barrier();
    asm volatile("" ::: "memory");  // fence: no LDS reads hoist above barrier
    const u16* KbT = &Ks[cur][0];
    const u16* VbT = &Vts[cur][0];

    // ---- QK cluster: S^T = K * Q^T (two 32-key blocks, 16 mfma) ----
    f32x16 St0 = {}, St1 = {};
    __builtin_amdgcn_s_setprio(1);
#pragma unroll
    for (int dht = 0; dht < 8; ++dht) {
      U128 kf;
      kf.i = *(const int4*)(KbT + (kinv ^ (unsigned)(dht << 4)));
      St0 = mfma32(kf, qf[dht], St0);
    }
#pragma unroll
    for (int dht = 0; dht < 8; ++dht) {
      U128 kf;
      kf.i = *(const int4*)(KbT + (kinv ^ (unsigned)(dht << 4)) + 4096);
      St1 = mfma32(kf, qf[dht], St1);
    }
    __builtin_amdgcn_s_setprio(0);

    // PV helper: O[dht] += V^T[dht-block] * pf  (4 reads + 4 mfma)
    auto pv = [&](int kt, const U128& pfk) {
#pragma unroll
      for (int dht = 0; dht < 4; ++dht) {
        U128 vf;
        vf.i = *(const int4*)(VbT + (vinv ^ (unsigned)(kt << 4)) + dht * 2048);
        O[dht] = mfma32(vf, pfk, O[dht]);
      }
    };
    // pf builder: pack 8 p-values to bf16 pairs, lane-half exchange in-register
    auto mkpf = [&](const float* p) {
      unsigned w0 = pk2bf(p[0], p[1]);
      unsigned w1 = pk2bf(p[2], p[3]);
      unsigned w2 = pk2bf(p[4], p[5]);
      unsigned w3 = pk2bf(p[6], p[7]);
      plswap(w0, w2);
      plswap(w1, w3);
      U128 r; r.i = make_int4(w0, w1, w2, w3);
      return r;
    };

    // ---- SM0: exp2 of St0 (keys 0..31), 4-way partial sums ----
    float p0[16];
#pragma unroll
    for (int r = 0; r < 16; r += 4) {
      p0[r + 0] = EXP2F(St0[r + 0]); ls0 += p0[r + 0];
      p0[r + 1] = EXP2F(St0[r + 1]); ls1 += p0[r + 1];
      p0[r + 2] = EXP2F(St0[r + 2]); ls2 += p0[r + 2];
      p0[r + 3] = EXP2F(St0[r + 3]); ls3 += p0[r + 3];
    }
    U128 pf0 = mkpf(&p0[0]);
    U128 pf1 = mkpf(&p0[8]);

    pv(0, pf0);  // overlaps with SM1a below (no fences between)

    // ---- SM1a: exp2 of St1 low half ----
    float p1[16];
#pragma unroll
    for (int r = 0; r < 8; r += 4) {
      p1[r + 0] = EXP2F(St1[r + 0]); ls0 += p1[r + 0];
      p1[r + 1] = EXP2F(St1[r + 1]); ls1 += p1[r + 1];
      p1[r + 2] = EXP2F(St1[r + 2]); ls2 += p1[r + 2];
      p1[r + 3] = EXP2F(St1[r + 3]); ls3 += p1[r + 3];
    }
    pv(1, pf1);

    // ---- SM1b: exp2 of St1 high half + pack ----
#pragma unroll
    for (int r = 8; r < 16; r += 4) {
      p1[r + 0] = EXP2F(St1[r + 0]); ls0 += p1[r + 0];
      p1[r + 1] = EXP2F(St1[r + 1]); ls1 += p1[r + 1];
      p1[r + 2] = EXP2F(St1[r + 2]); ls2 += p1[r + 2];
      p1[r + 3] = EXP2F(St1[r + 3]); ls3 += p1[r + 3];
    }
    U128 pf2 = mkpf(&p1[0]);
    U128 pf3 = mkpf(&p1[8]);

    __builtin_amdgcn_s_setprio(1);
    pv(2, pf2);
    pv(3, pf3);
    __builtin_amdgcn_s_setprio(0);

    asm volatile("" ::: "memory");  // fence: all LDS reads done before re-stage
    __builtin_amdgcn_s_barrier();
    cur ^= 1;
  }

  // finalize: l[q] = own + partner half; divide; packed dwordx2 stores
  float lsum = (ls0 + ls1) + (ls2 + ls3);
  float ltot = lsum + __shfl_xor(lsum, 32);
  float inv = 1.f / ltot;
  long orow = (long)b * 2048 + q0 + l31;
  u16* ob = attn + orow * 2048 + hd * 128;
#pragma unroll
  for (int dht = 0; dht < 4; ++dht)
#pragma unroll
    for (int g = 0; g < 4; ++g) {
      int dh = dht * 32 + g * 8 + h * 4;  // rows (reg&3)+8*(reg>>2)+4h, regs 4g..4g+3
      float v0 = O[dht][4 * g + 0] * inv, v1 = O[dht][4 * g + 1] * inv;
      float v2 = O[dht][4 * g + 2] * inv, v3 = O[dht][4 * g + 3] * inv;
      uint2 pkd;
      pkd.x = pk2bf(v0, v1);
      pkd.y = pk2bf(v2, v3);
      *(uint2*)(ob + dh) = pkd;
    }
}

extern "C" void kernel_launch(void* const* d_in, const int* in_sizes, int n_in,
                              void* d_out, int out_size, void* d_ws, size_t ws_size,
                              hipStream_t stream) {
  const float* x    = (const float*)d_in[0];
  const float* Wqkv = (const float*)d_in[1];
  const float* bqkv = (const float*)d_in[2];
  const float* Wout = (const float*)d_in[3];
  const float* bout = (const float*)d_in[4];
  float* out = (float*)d_out;
  char* ws = (char*)d_ws;

  // Workspace overlay (peak 75,497,472 B in ws; d_out = 33.55 MB doubles as scratch):
  //   phase A (k_pre + GEMM1):
  //            xb (bf16 x, 16.78 MB)  -> d_out[0, 16.78M)  [dead after GEMM1]
  //            wqkvt (25.17 MB)       -> ws[0, 25165824)   [dead after GEMM1]
  //            qb  [bh][s][dh]        -> ws[25165824, 41943040)
  //            kb  [bh][s][dh]        -> ws[41943040, 58720256)
  //            vt  [bh][stile][d][s]  -> ws[58720256, 75497472)  (GEMM1 writes directly)
  //   phase B (flash + GEMM2):
  //            woutt (8.39 MB)        -> ws[0, 8388608)    (flash tail blocks; wqkvt dead)
  //            attnb (16.78 MB)       -> ws[8388608, 25165824)
  //   qb/kb/vt dead before GEMM2 writes d_out; d_out fully free from flash on.
  if (ws_size < 75497472u) return;  // diagnostic guard: fail cleanly, not fault

  u16* xb    = (u16*)d_out;
  u16* wqkvt = (u16*)(ws);
  u16* qbuf  = (u16*)(ws + 25165824);
  u16* kbuf  = (u16*)(ws + 41943040);
  u16* vtb   = (u16*)(ws + 58720256);
  u16* woutt = (u16*)(ws);             // after GEMM1 (wqkvt dead)
  u16* attnb = (u16*)(ws + 8388608);   // after GEMM1

  // 4 launches: pre(conv+WqkvT) -> GEMM1(+V^T epi) -> flash(+WoutT) -> GEMM2
  k_pre<<<11264, 256, 0, stream>>>(x, xb, Wqkv, wqkvt);
  k_gemm_bt<1><<<dim3(48, 32), 256, 0, stream>>>(xb, wqkvt, bqkv, nullptr,
                                                 qbuf, kbuf, vtb, 0, 4096, 6144, 2048);
  k_flash<<<dim3(8, 96), 512, 0, stream>>>(qbuf, kbuf, vtb, attnb, Wout, woutt);
  k_gemm_bt<0><<<dim3(16, 32), 256, 0, stream>>>(attnb, woutt, bout, out,
                                                 nullptr, nullptr, nullptr, 0, 4096, 2048, 2048);
}

// Round 8
// 370.950 us; speedup vs baseline: 1.0070x; 1.0070x over previous
//
#include <hip/hip_runtime.h>
#include <type_traits>
#include <utility>

#define DI __device__ __forceinline__

typedef unsigned short u16;
typedef float f32x4 __attribute__((ext_vector_type(4)));
typedef float f32x16 __attribute__((ext_vector_type(16)));
typedef short s16x8 __attribute__((ext_vector_type(8)));
typedef __bf16 bf16x8 __attribute__((ext_vector_type(8)));

// ---- pick whichever vector type the gfx950 bf16 MFMA builtin accepts ----
template <typename V, typename = void>
struct mfma_ok : std::false_type {};
template <typename V>
struct mfma_ok<V, std::void_t<decltype(__builtin_amdgcn_mfma_f32_16x16x32_bf16(
    std::declval<V>(), std::declval<V>(), std::declval<f32x4>(), 0, 0, 0))>>
    : std::true_type {};
using frag_t = std::conditional_t<mfma_ok<bf16x8>::value, bf16x8, s16x8>;

union U128 {
  int4 i;
  frag_t f;
  u16 s[8];
};

DI f32x4 mfma16(const U128& a, const U128& b, f32x4 c) {
  return __builtin_amdgcn_mfma_f32_16x16x32_bf16(a.f, b.f, c, 0, 0, 0);
}
DI f32x16 mfma32(const U128& a, const U128& b, f32x16 c) {
  return __builtin_amdgcn_mfma_f32_32x32x16_bf16(a.f, b.f, c, 0, 0, 0);
}

DI u16 f2b(float x) {  // fp32 -> bf16 RNE (finite inputs)
  union { float f; unsigned u; } v; v.f = x;
  unsigned r = v.u + 0x7FFFu + ((v.u >> 16) & 1u);
  return (u16)(r >> 16);
}

// Packed fp32 pair -> bf16x2 in one u32 (compiler emits v_cvt_pk_bf16_f32).
DI unsigned pk2bf(float a, float b) {
  unsigned short ua = __builtin_bit_cast(unsigned short, (__bf16)a);
  unsigned short ub = __builtin_bit_cast(unsigned short, (__bf16)b);
  return (unsigned)ua | ((unsigned)ub << 16);
}

#if __has_builtin(__builtin_amdgcn_exp2f)
#define EXP2F __builtin_amdgcn_exp2f
#else
#define EXP2F exp2f
#endif

// v_permlane32_swap_b32 via inline asm.
// After: lo = {h0: own lo | h1: partner hi}, hi = {h0: partner lo | h1: own hi}
DI void plswap(unsigned& lo, unsigned& hi) {
  asm("v_permlane32_swap_b32 %0, %1" : "+v"(lo), "+v"(hi));
}

typedef __attribute__((address_space(1))) void gas_t;
typedef __attribute__((address_space(3))) void las_t;
DI void gll16(const void* g, void* l) {  // async global->LDS, 16B/lane
  __builtin_amdgcn_global_load_lds((gas_t*)g, (las_t*)l, 16, 0, 0);
}

// cs * log2(e): folded into Q at GEMM1 routing so flash uses exp2 directly.
#define QSCALE 0.12751791437603762f  /* (1/sqrt(128)) * 1.4426950408889634 */

// ---- shared 64x64 fp32->bf16 transpose tile (used by k_pre and k_flash tail) ----
DI void transpose_tile(const float* __restrict__ in, u16* __restrict__ out,
                       int R, int C, int bx, int by, int t, u16 (*Tb)[68]) {
  long r0 = (long)by * 64, c0 = (long)bx * 64;
  int cq = (t & 15) * 4, rr = t >> 4;
#pragma unroll
  for (int it = 0; it < 4; ++it) {
    int r = rr + it * 16;
    float4 v = *(const float4*)(in + (r0 + r) * C + c0 + cq);
    Tb[r][cq + 0] = f2b(v.x); Tb[r][cq + 1] = f2b(v.y);
    Tb[r][cq + 2] = f2b(v.z); Tb[r][cq + 3] = f2b(v.w);
  }
  __syncthreads();
#pragma unroll
  for (int it = 0; it < 2; ++it) {
    int ci = it * 256 + t;
    int cc = ci >> 3, ch = ci & 7, rb = ch * 8;
    unsigned p0 = Tb[rb + 0][cc] | ((unsigned)Tb[rb + 1][cc] << 16);
    unsigned p1 = Tb[rb + 2][cc] | ((unsigned)Tb[rb + 3][cc] << 16);
    unsigned p2 = Tb[rb + 4][cc] | ((unsigned)Tb[rb + 5][cc] << 16);
    unsigned p3 = Tb[rb + 6][cc] | ((unsigned)Tb[rb + 7][cc] << 16);
    *(int4*)(out + (c0 + cc) * R + r0 + rb) = make_int4(p0, p1, p2, p3);
  }
}

// ---------------- fused preprocessing: x->bf16 + Wqkv transpose ----------------
// blocks [0,8192): conv of x (8192*256 float4s exactly)
// blocks [8192,11264): Wqkv [2048][6144] -> wqkvt [6144][2048] (96x32 tiles)
__global__ __launch_bounds__(256) void k_pre(const float* __restrict__ x,
                                             u16* __restrict__ xb,
                                             const float* __restrict__ Wqkv,
                                             u16* __restrict__ wqkvt) {
  __shared__ __attribute__((aligned(16))) u16 Tb[64][68];
  int bid = blockIdx.x, t = threadIdx.x;
  if (bid < 8192) {
    int i = bid * 256 + t;
    float4 v = ((const float4*)x)[i];
    ushort4 o;
    o.x = f2b(v.x); o.y = f2b(v.y); o.z = f2b(v.z); o.w = f2b(v.w);
    ((ushort4*)xb)[i] = o;
    return;
  }
  int idx = bid - 8192;  // [0, 3072) = 96 x 32 tiles
  transpose_tile(Wqkv, wqkvt, 2048, 6144, idx % 96, idx / 96, t, Tb);
}

// ---------------- C[M][N] = A[M][K] * Bt[N][K]^T + bias (128x128 tile) ----------------
// BK=64, XOR chunk swizzle (conflict-free on the GEMM phase).
// Proven 986 TF @ GEMM1 shape via ~2.7 blocks/CU TLP (m97-family structure).
// MODE 0: fp32 packed-pair out to Cout (GEMM2).
// MODE 1: bf16 routed out (GEMM1): per-128-col group -> q/k of head grp/3;
//         V groups (rsel==2) transposed through LDS and written DIRECTLY in the
//         TILED vt layout [bh][stile][d][s%128]. (Epilogue LDS bounce costs a
//         fixed 262144 conflict-cycles total across the dispatch ~= 0.1us: not
//         a lever, measured R6=R7 identical.)
template <int MODE>
__global__ __launch_bounds__(256, 4) void k_gemm_bt(const u16* __restrict__ A,
                                                    const u16* __restrict__ Bt,
                                                    const float* __restrict__ bias,
                                                    void* __restrict__ Cout,
                                                    u16* __restrict__ qb,
                                                    u16* __restrict__ kbv,
                                                    u16* __restrict__ vt,
                                                    int n_off,
                                                    int M, int N, int K) {
  // SM: As=[0,8192) u16, Bs=[8192,16384). V-epilogue reuses SM as a d-major
  // padded [128][130] tile (16640 u16 = 33280 B).
  __shared__ __attribute__((aligned(16))) u16 SM[16640];
  u16* As = SM;
  u16* Bs = SM + 8192;
  int t = threadIdx.x;
  int lane = t & 63, w = t >> 6, quad = lane >> 4, l15 = lane & 15;
  long m0 = (long)blockIdx.y * 128, n0 = n_off + (long)blockIdx.x * 128;
  int wr = (w >> 1) * 64, wc = (w & 1) * 64;
  int sw = l15 & 7;
  f32x4 acc[4][4] = {};
  for (int k0 = 0; k0 < K; k0 += 64) {
    __syncthreads();
#pragma unroll
    for (int it = 0; it < 4; ++it) {
      int ci = it * 256 + t;
      int row = ci >> 3, cl = (ci & 7) ^ (row & 7);
      gll16(A + (m0 + row) * K + k0 + cl * 8, As + ci * 8);
      gll16(Bt + (n0 + row) * K + k0 + cl * 8, Bs + ci * 8);
    }
    __syncthreads();
#pragma unroll
    for (int kk = 0; kk < 2; ++kk) {
      U128 a[4], b[4];
#pragma unroll
      for (int i = 0; i < 4; ++i)
        a[i].i = *(const int4*)(As + (wr + i * 16 + l15) * 64 + (((kk * 4 + quad) ^ sw) << 3));
#pragma unroll
      for (int j = 0; j < 4; ++j)
        b[j].i = *(const int4*)(Bs + (wc + j * 16 + l15) * 64 + (((kk * 4 + quad) ^ sw) << 3));
#pragma unroll
      for (int i = 0; i < 4; ++i)
#pragma unroll
        for (int j = 0; j < 4; ++j)
          acc[i][j] = mfma16(a[i], b[j], acc[i][j]);
    }
  }
  float bj[4];
#pragma unroll
  for (int j = 0; j < 4; ++j) bj[j] = bias[n0 + wc + j * 16 + l15];

  // routing (block-uniform: n0 block-uniform, wc<128 so grp = n0>>7)
  int hidx = (int)(n0 / 384);
  int rsel = (int)(n0 - hidx * 384) >> 7;  // 0=Q 1=K 2=V

  if (MODE == 1 && rsel == 2) {
    // ---- V^T direct write through LDS, tiled-coalesced ----
    __syncthreads();  // all waves done reading As/Bs (SM reused as [128][130])
#pragma unroll
    for (int i = 0; i < 4; ++i)
#pragma unroll
      for (int rr2 = 0; rr2 < 4; ++rr2) {
        int m = wr + i * 16 + quad * 4 + rr2;  // s within tile
#pragma unroll
        for (int j = 0; j < 4; ++j)
          SM[(wc + j * 16 + l15) * 130 + m] = f2b(acc[i][j][rr2] + bj[j]);
      }
    __syncthreads();
    int bidx = (int)(m0 >> 11);
    int stile = (int)((m0 & 2047) >> 7);
    u16* vtile = vt + (long)(bidx * 16 + hidx) * 262144 + stile * 16384;
    const unsigned* sm32 = (const unsigned*)SM;
#pragma unroll
    for (int it = 0; it < 8; ++it) {
      int ci = it * 256 + t;               // [0,2048)
      int d = ci >> 4, sb = (ci & 15) * 8; // lanes: consecutive s -> coalesced
      int base = (d * 130 + sb) >> 1;      // dword-aligned (130,sb even)
      *(int4*)(vtile + d * 128 + sb) =
          make_int4(sm32[base], sm32[base + 1], sm32[base + 2], sm32[base + 3]);
    }
    return;
  }

  u16* route = (MODE == 1) ? (rsel == 0 ? qb : kbv) : nullptr;

#pragma unroll
  for (int i = 0; i < 4; ++i) {
#pragma unroll
    for (int rr2 = 0; rr2 < 4; ++rr2) {
      long row = m0 + wr + i * 16 + quad * 4 + rr2;
#pragma unroll
      for (int j = 0; j < 4; ++j) {
        float v = acc[i][j][rr2] + bj[j];
        if (MODE == 1) {
          if (rsel == 0) v *= QSCALE;  // pre-scale Q (block-uniform branch)
          int bidx = (int)(row >> 11), s = (int)(row & 2047);
          long obase = ((long)(bidx * 16 + hidx) * 2048 + s) * 128;
          int dh = wc + j * 16 + l15;
          unsigned pb = f2b(v);
          unsigned other = __shfl_xor(pb, 1);
          if (!(l15 & 1))
            ((unsigned*)route)[(obase + dh) >> 1] = pb | (other << 16);
        } else {
          long col = n0 + wc + j * 16 + l15;
          unsigned bits = __float_as_uint(v);
          unsigned other = __shfl_xor(bits, 1);
          if (!(l15 & 1)) {
            uint2 pr; pr.x = bits; pr.y = other;
            *(uint2*)((float*)Cout + row * N + col) = pr;
          }
        }
      }
    }
  }
}

// ---------------- flash attention: 32x32x16, S^T, dbuf + counted vmcnt ----------------
// 8 waves/block (512 thr), 256 q-rows/block, 256 main blocks (1/CU).
// Round-8: XCD/bh-grouping block remap (T1 adapted). Main-region dispatch index
// d = by*8+bx; logical assignment bh=(d&7)+((d>>6)<<3), j=(d>>3)&7 is bijective
// on [0,256) and puts all 8 q-blocks of a bh on ONE XCD (XCD = d%8 round-robin):
// each XCD's L2 holds a 4-bh/4MB K+V resident set instead of thrashing 32MB.
// Expect FETCH ~75MB -> ~50MB; dur improves iff staging latency was exposed.
// Intra-tile interleave: QK0+QK1 -> SM0 -> PV0 -> SM1a -> PV1 -> SM1b -> PV2+PV3.
// by>=32: Wout-transpose tail blocks, 2 tiles per 512-thread block (woutt
// overlaps wqkvt which is dead after GEMM1).
__global__ __launch_bounds__(512, 2) void k_flash(const u16* __restrict__ qb,
                                                  const u16* __restrict__ kb,
                                                  const u16* __restrict__ vt,
                                                  u16* __restrict__ attn,
                                                  const float* __restrict__ Wout,
                                                  u16* __restrict__ woutt) {
  __shared__ __attribute__((aligned(16))) u16 Ks[2][64 * 128];   // [key][dh], chunk-swizzled
  __shared__ __attribute__((aligned(16))) u16 Vts[2][128 * 64];  // [dh][key], chunk-swizzled
  if (blockIdx.y >= 32) {  // fused Wout transpose tail (2 tiles per block)
    int half = threadIdx.x >> 8, tt = threadIdx.x & 255;
    u16 (*Tb)[68] = (u16(*)[68])(&Ks[0][0] + half * 64 * 68);
    int u = ((blockIdx.y - 32) * 8 + blockIdx.x) * 2 + half;  // [0, 1024)
    transpose_tile(Wout, woutt, 2048, 2048, u & 31, u >> 5, tt, Tb);
    return;
  }
  int t = threadIdx.x;
  int lane = t & 63, w = t >> 6, l31 = lane & 31, h = lane >> 5;
  // XCD/bh-grouping remap (bijective; see header comment)
  int d0 = blockIdx.y * 8 + blockIdx.x;        // dispatch index [0,256)
  int bh = (d0 & 7) + ((d0 >> 6) << 3);        // [0,32)
  int jq = (d0 >> 3) & 7;                      // q-tile [0,8)
  int q0 = jq * 256 + w * 32;
  int b = bh >> 4, hd = bh & 15;

  // Q B-frags from contiguous qb: lane holds Q[q0+l31][dht*16 + h*8 + j]
  const u16* qbase = qb + ((long)bh * 2048 + q0 + l31) * 128;
  U128 qf[8];
#pragma unroll
  for (int dht = 0; dht < 8; ++dht)
    qf[dht].i = *(const int4*)(qbase + dht * 16 + h * 8);
  // Drain Q loads so no q-load vmcnt dependency is carried into the loop.
  __syncthreads();

  f32x16 O[4] = {};  // O^T: col=q, rows=dh (4 blocks of 32)
  float ls0 = 0.f, ls1 = 0.f, ls2 = 0.f, ls3 = 0.f;
  const u16* kbh = kb + (long)bh * 2048 * 128;
  long vbase = (long)bh * 262144;  // tiled vt: [bh][stile][d][s%128]

  // Merged per-lane LDS read bases (u16 units). Verified algebra:
  //  K:  row*128 + ((dht*2+h)^(row&7))*8  ==  kinv ^ (dht<<4)  (+4096 for kb2=1)
  //      kinv = l31<<7 ^ ((l31&7)<<3) ^ (h<<3)
  //  V:  vrow*64 + ((kt*2+h)^(vrow&7))*8 ==  vinv ^ (kt<<4)  (+dht*2048)
  //      vinv = l31<<6 ^ ((l31&7)<<3) ^ (h<<3)
  unsigned swx = (unsigned)(((l31 & 7) << 3) ^ (h << 3));
  unsigned kinv = ((unsigned)l31 << 7) ^ swx;
  unsigned vinv = ((unsigned)l31 << 6) ^ swx;

  // stage one 64-key tile: 4 gll16/thread (2 K rows + 2 V^T rows) @512 threads
  auto stage = [&](int buf, int k0) {
#pragma unroll
    for (int it = 0; it < 2; ++it) {  // K tile: 64 keys x 128 dh
      int ci = it * 512 + t;
      int key = ci >> 4, cp = ci & 15, cl = cp ^ (key & 7);
      gll16(kbh + (long)(k0 + key) * 128 + cl * 8, &Ks[buf][0] + ci * 8);
    }
#pragma unroll
    for (int it = 0; it < 2; ++it) {  // V^T tile: 128 dh x 64 keys (tiled vt)
      int ci = it * 512 + t;
      int d = ci >> 3, cp = ci & 7, cl = cp ^ (d & 7);
      gll16(vt + vbase + ((k0 >> 7) << 14) + d * 128 + (k0 & 64) + cl * 8,
            &Vts[buf][0] + ci * 8);
    }
  };

  stage(0, 0);
  int cur = 0;
  for (int k0 = 0; k0 < 2048; k0 += 64) {
    if (k0 + 64 < 2048) {
      stage(cur ^ 1, k0 + 64);                          // prefetch next tile
      asm volatile("s_waitcnt vmcnt(4)" ::: "memory");  // current tile landed
    } else {
      asm volatile("s_waitcnt vmcnt(0)" ::: "memory");  // last tile: drain
    }
    __builtin_amdgcn_s_barrier();
    asm volatile("" ::: "memory");  // fence: no LDS reads hoist above barrier
    const u16* KbT = &Ks[cur][0];
    const u16* VbT = &Vts[cur][0];

    // ---- QK cluster: S^T = K * Q^T (two 32-key blocks, 16 mfma) ----
    f32x16 St0 = {}, St1 = {};
    __builtin_amdgcn_s_setprio(1);
#pragma unroll
    for (int dht = 0; dht < 8; ++dht) {
      U128 kf;
      kf.i = *(const int4*)(KbT + (kinv ^ (unsigned)(dht << 4)));
      St0 = mfma32(kf, qf[dht], St0);
    }
#pragma unroll
    for (int dht = 0; dht < 8; ++dht) {
      U128 kf;
      kf.i = *(const int4*)(KbT + (kinv ^ (unsigned)(dht << 4)) + 4096);
      St1 = mfma32(kf, qf[dht], St1);
    }
    __builtin_amdgcn_s_setprio(0);

    // PV helper: O[dht] += V^T[dht-block] * pf  (4 reads + 4 mfma)
    auto pv = [&](int kt, const U128& pfk) {
#pragma unroll
      for (int dht = 0; dht < 4; ++dht) {
        U128 vf;
        vf.i = *(const int4*)(VbT + (vinv ^ (unsigned)(kt << 4)) + dht * 2048);
        O[dht] = mfma32(vf, pfk, O[dht]);
      }
    };
    // pf builder: pack 8 p-values to bf16 pairs, lane-half exchange in-register
    auto mkpf = [&](const float* p) {
      unsigned w0 = pk2bf(p[0], p[1]);
      unsigned w1 = pk2bf(p[2], p[3]);
      unsigned w2 = pk2bf(p[4], p[5]);
      unsigned w3 = pk2bf(p[6], p[7]);
      plswap(w0, w2);
      plswap(w1, w3);
      U128 r; r.i = make_int4(w0, w1, w2, w3);
      return r;
    };

    // ---- SM0: exp2 of St0 (keys 0..31), 4-way partial sums ----
    float p0[16];
#pragma unroll
    for (int r = 0; r < 16; r += 4) {
      p0[r + 0] = EXP2F(St0[r + 0]); ls0 += p0[r + 0];
      p0[r + 1] = EXP2F(St0[r + 1]); ls1 += p0[r + 1];
      p0[r + 2] = EXP2F(St0[r + 2]); ls2 += p0[r + 2];
      p0[r + 3] = EXP2F(St0[r + 3]); ls3 += p0[r + 3];
    }
    U128 pf0 = mkpf(&p0[0]);
    U128 pf1 = mkpf(&p0[8]);

    pv(0, pf0);  // overlaps with SM1a below (no fences between)

    // ---- SM1a: exp2 of St1 low half ----
    float p1[16];
#pragma unroll
    for (int r = 0; r < 8; r += 4) {
      p1[r + 0] = EXP2F(St1[r + 0]); ls0 += p1[r + 0];
      p1[r + 1] = EXP2F(St1[r + 1]); ls1 += p1[r + 1];
      p1[r + 2] = EXP2F(St1[r + 2]); ls2 += p1[r + 2];
      p1[r + 3] = EXP2F(St1[r + 3]); ls3 += p1[r + 3];
    }
    pv(1, pf1);

    // ---- SM1b: exp2 of St1 high half + pack ----
#pragma unroll
    for (int r = 8; r < 16; r += 4) {
      p1[r + 0] = EXP2F(St1[r + 0]); ls0 += p1[r + 0];
      p1[r + 1] = EXP2F(St1[r + 1]); ls1 += p1[r + 1];
      p1[r + 2] = EXP2F(St1[r + 2]); ls2 += p1[r + 2];
      p1[r + 3] = EXP2F(St1[r + 3]); ls3 += p1[r + 3];
    }
    U128 pf2 = mkpf(&p1[0]);
    U128 pf3 = mkpf(&p1[8]);

    __builtin_amdgcn_s_setprio(1);
    pv(2, pf2);
    pv(3, pf3);
    __builtin_amdgcn_s_setprio(0);

    asm volatile("" ::: "memory");  // fence: all LDS reads done before re-stage
    __builtin_amdgcn_s_barrier();
    cur ^= 1;
  }

  // finalize: l[q] = own + partner half; divide; packed dwordx2 stores
  float lsum = (ls0 + ls1) + (ls2 + ls3);
  float ltot = lsum + __shfl_xor(lsum, 32);
  float inv = 1.f / ltot;
  long orow = (long)b * 2048 + q0 + l31;
  u16* ob = attn + orow * 2048 + hd * 128;
#pragma unroll
  for (int dht = 0; dht < 4; ++dht)
#pragma unroll
    for (int g = 0; g < 4; ++g) {
      int dh = dht * 32 + g * 8 + h * 4;  // rows (reg&3)+8*(reg>>2)+4h, regs 4g..4g+3
      float v0 = O[dht][4 * g + 0] * inv, v1 = O[dht][4 * g + 1] * inv;
      float v2 = O[dht][4 * g + 2] * inv, v3 = O[dht][4 * g + 3] * inv;
      uint2 pkd;
      pkd.x = pk2bf(v0, v1);
      pkd.y = pk2bf(v2, v3);
      *(uint2*)(ob + dh) = pkd;
    }
}

extern "C" void kernel_launch(void* const* d_in, const int* in_sizes, int n_in,
                              void* d_out, int out_size, void* d_ws, size_t ws_size,
                              hipStream_t stream) {
  const float* x    = (const float*)d_in[0];
  const float* Wqkv = (const float*)d_in[1];
  const float* bqkv = (const float*)d_in[2];
  const float* Wout = (const float*)d_in[3];
  const float* bout = (const float*)d_in[4];
  float* out = (float*)d_out;
  char* ws = (char*)d_ws;

  // Workspace overlay (peak 75,497,472 B in ws; d_out = 33.55 MB doubles as scratch):
  //   phase A (k_pre + GEMM1):
  //            xb (bf16 x, 16.78 MB)  -> d_out[0, 16.78M)  [dead after GEMM1]
  //            wqkvt (25.17 MB)       -> ws[0, 25165824)   [dead after GEMM1]
  //            qb  [bh][s][dh]        -> ws[25165824, 41943040)
  //            kb  [bh][s][dh]        -> ws[41943040, 58720256)
  //            vt  [bh][stile][d][s]  -> ws[58720256, 75497472)  (GEMM1 writes directly)
  //   phase B (flash + GEMM2):
  //            woutt (8.39 MB)        -> ws[0, 8388608)    (flash tail blocks; wqkvt dead)
  //            attnb (16.78 MB)       -> ws[8388608, 25165824)
  //   qb/kb/vt dead before GEMM2 writes d_out; d_out fully free from flash on.
  if (ws_size < 75497472u) return;  // diagnostic guard: fail cleanly, not fault

  u16* xb    = (u16*)d_out;
  u16* wqkvt = (u16*)(ws);
  u16* qbuf  = (u16*)(ws + 25165824);
  u16* kbuf  = (u16*)(ws + 41943040);
  u16* vtb   = (u16*)(ws + 58720256);
  u16* woutt = (u16*)(ws);             // after GEMM1 (wqkvt dead)
  u16* attnb = (u16*)(ws + 8388608);   // after GEMM1

  // 4 launches: pre(conv+WqkvT) -> GEMM1(+V^T epi) -> flash(+WoutT) -> GEMM2
  k_pre<<<11264, 256, 0, stream>>>(x, xb, Wqkv, wqkvt);
  k_gemm_bt<1><<<dim3(48, 32), 256, 0, stream>>>(xb, wqkvt, bqkv, nullptr,
                                                 qbuf, kbuf, vtb, 0, 4096, 6144, 2048);
  k_flash<<<dim3(8, 96), 512, 0, stream>>>(qbuf, kbuf, vtb, attnb, Wout, woutt);
  k_gemm_bt<0><<<dim3(16, 32), 256, 0, stream>>>(attnb, woutt, bout, out,
                                                 nullptr, nullptr, nullptr, 0, 4096, 2048, 2048);
}

// Round 10
// 355.505 us; speedup vs baseline: 1.0508x; 1.0434x over previous
//
#include <hip/hip_runtime.h>
#include <type_traits>
#include <utility>

#define DI __device__ __forceinline__

typedef unsigned short u16;
typedef float f32x4 __attribute__((ext_vector_type(4)));
typedef float f32x16 __attribute__((ext_vector_type(16)));
typedef short s16x8 __attribute__((ext_vector_type(8)));
typedef __bf16 bf16x8 __attribute__((ext_vector_type(8)));

// ---- pick whichever vector type the gfx950 bf16 MFMA builtin accepts ----
template <typename V, typename = void>
struct mfma_ok : std::false_type {};
template <typename V>
struct mfma_ok<V, std::void_t<decltype(__builtin_amdgcn_mfma_f32_16x16x32_bf16(
    std::declval<V>(), std::declval<V>(), std::declval<f32x4>(), 0, 0, 0))>>
    : std::true_type {};
using frag_t = std::conditional_t<mfma_ok<bf16x8>::value, bf16x8, s16x8>;

union U128 {
  int4 i;
  frag_t f;
  u16 s[8];
};

DI f32x4 mfma16(const U128& a, const U128& b, f32x4 c) {
  return __builtin_amdgcn_mfma_f32_16x16x32_bf16(a.f, b.f, c, 0, 0, 0);
}
DI f32x16 mfma32(const U128& a, const U128& b, f32x16 c) {
  return __builtin_amdgcn_mfma_f32_32x32x16_bf16(a.f, b.f, c, 0, 0, 0);
}

DI u16 f2b(float x) {  // fp32 -> bf16 RNE (finite inputs)
  union { float f; unsigned u; } v; v.f = x;
  unsigned r = v.u + 0x7FFFu + ((v.u >> 16) & 1u);
  return (u16)(r >> 16);
}

// Packed fp32 pair -> bf16x2 in one u32 (compiler emits v_cvt_pk_bf16_f32).
DI unsigned pk2bf(float a, float b) {
  unsigned short ua = __builtin_bit_cast(unsigned short, (__bf16)a);
  unsigned short ub = __builtin_bit_cast(unsigned short, (__bf16)b);
  return (unsigned)ua | ((unsigned)ub << 16);
}

// exp2: MUST go through the builtin (or libm) — R9 post-mortem: raw
// `v_exp_f32` inline asm violates the ISA's trans-op wait-state rule (1 wait
// state before a VALU consumer); the hazard recognizer can't see inside an
// asm blob, so consumers intermittently read the stale register -> absmax
// 3.7e-2 corruption. The builtin path gets compiler hazard handling.
#if __has_builtin(__builtin_amdgcn_exp2f)
#define EXP2F __builtin_amdgcn_exp2f
#else
#define EXP2F exp2f
#endif

// v_permlane32_swap_b32 via inline asm.
// After: lo = {h0: own lo | h1: partner hi}, hi = {h0: partner lo | h1: own hi}
DI void plswap(unsigned& lo, unsigned& hi) {
  asm("v_permlane32_swap_b32 %0, %1" : "+v"(lo), "+v"(hi));
}

typedef __attribute__((address_space(1))) void gas_t;
typedef __attribute__((address_space(3))) void las_t;
DI void gll16(const void* g, void* l) {  // async global->LDS, 16B/lane
  __builtin_amdgcn_global_load_lds((gas_t*)g, (las_t*)l, 16, 0, 0);
}

// cs * log2(e): folded into Q at GEMM1 routing so flash uses exp2 directly.
#define QSCALE 0.12751791437603762f  /* (1/sqrt(128)) * 1.4426950408889634 */

// ---- shared 64x64 fp32->bf16 transpose tile (used by k_pre and k_flash tail) ----
DI void transpose_tile(const float* __restrict__ in, u16* __restrict__ out,
                       int R, int C, int bx, int by, int t, u16 (*Tb)[68]) {
  long r0 = (long)by * 64, c0 = (long)bx * 64;
  int cq = (t & 15) * 4, rr = t >> 4;
#pragma unroll
  for (int it = 0; it < 4; ++it) {
    int r = rr + it * 16;
    float4 v = *(const float4*)(in + (r0 + r) * C + c0 + cq);
    Tb[r][cq + 0] = f2b(v.x); Tb[r][cq + 1] = f2b(v.y);
    Tb[r][cq + 2] = f2b(v.z); Tb[r][cq + 3] = f2b(v.w);
  }
  __syncthreads();
#pragma unroll
  for (int it = 0; it < 2; ++it) {
    int ci = it * 256 + t;
    int cc = ci >> 3, ch = ci & 7, rb = ch * 8;
    unsigned p0 = Tb[rb + 0][cc] | ((unsigned)Tb[rb + 1][cc] << 16);
    unsigned p1 = Tb[rb + 2][cc] | ((unsigned)Tb[rb + 3][cc] << 16);
    unsigned p2 = Tb[rb + 4][cc] | ((unsigned)Tb[rb + 5][cc] << 16);
    unsigned p3 = Tb[rb + 6][cc] | ((unsigned)Tb[rb + 7][cc] << 16);
    *(int4*)(out + (c0 + cc) * R + r0 + rb) = make_int4(p0, p1, p2, p3);
  }
}

// ---------------- fused preprocessing: x->bf16 + Wqkv transpose ----------------
// blocks [0,8192): conv of x (8192*256 float4s exactly)
// blocks [8192,11264): Wqkv [2048][6144] -> wqkvt [6144][2048] (96x32 tiles)
__global__ __launch_bounds__(256) void k_pre(const float* __restrict__ x,
                                             u16* __restrict__ xb,
                                             const float* __restrict__ Wqkv,
                                             u16* __restrict__ wqkvt) {
  __shared__ __attribute__((aligned(16))) u16 Tb[64][68];
  int bid = blockIdx.x, t = threadIdx.x;
  if (bid < 8192) {
    int i = bid * 256 + t;
    float4 v = ((const float4*)x)[i];
    ushort4 o;
    o.x = f2b(v.x); o.y = f2b(v.y); o.z = f2b(v.z); o.w = f2b(v.w);
    ((ushort4*)xb)[i] = o;
    return;
  }
  int idx = bid - 8192;  // [0, 3072) = 96 x 32 tiles
  transpose_tile(Wqkv, wqkvt, 2048, 6144, idx % 96, idx / 96, t, Tb);
}

// ---------------- C[M][N] = A[M][K] * Bt[N][K]^T + bias (128x128 tile) ----------------
// BK=64, XOR chunk swizzle (conflict-free on the GEMM phase).
// Proven 986 TF @ GEMM1 shape via ~2.7 blocks/CU TLP (m97-family structure).
// MODE 0: fp32 packed-pair out to Cout (GEMM2).
// MODE 1: bf16 routed out (GEMM1): per-128-col group -> q/k of head grp/3;
//         V groups (rsel==2) transposed through LDS and written DIRECTLY in the
//         TILED vt layout [bh][stile][d][s%128]. (Epilogue LDS bounce costs a
//         fixed 262144 conflict-cycles total across the dispatch ~= 0.1us: not
//         a lever, measured R6=R7=R8 identical.)
template <int MODE>
__global__ __launch_bounds__(256, 4) void k_gemm_bt(const u16* __restrict__ A,
                                                    const u16* __restrict__ Bt,
                                                    const float* __restrict__ bias,
                                                    void* __restrict__ Cout,
                                                    u16* __restrict__ qb,
                                                    u16* __restrict__ kbv,
                                                    u16* __restrict__ vt,
                                                    int n_off,
                                                    int M, int N, int K) {
  // SM: As=[0,8192) u16, Bs=[8192,16384). V-epilogue reuses SM as a d-major
  // padded [128][130] tile (16640 u16 = 33280 B).
  __shared__ __attribute__((aligned(16))) u16 SM[16640];
  u16* As = SM;
  u16* Bs = SM + 8192;
  int t = threadIdx.x;
  int lane = t & 63, w = t >> 6, quad = lane >> 4, l15 = lane & 15;
  long m0 = (long)blockIdx.y * 128, n0 = n_off + (long)blockIdx.x * 128;
  int wr = (w >> 1) * 64, wc = (w & 1) * 64;
  int sw = l15 & 7;
  f32x4 acc[4][4] = {};
  for (int k0 = 0; k0 < K; k0 += 64) {
    __syncthreads();
#pragma unroll
    for (int it = 0; it < 4; ++it) {
      int ci = it * 256 + t;
      int row = ci >> 3, cl = (ci & 7) ^ (row & 7);
      gll16(A + (m0 + row) * K + k0 + cl * 8, As + ci * 8);
      gll16(Bt + (n0 + row) * K + k0 + cl * 8, Bs + ci * 8);
    }
    __syncthreads();
#pragma unroll
    for (int kk = 0; kk < 2; ++kk) {
      U128 a[4], b[4];
#pragma unroll
      for (int i = 0; i < 4; ++i)
        a[i].i = *(const int4*)(As + (wr + i * 16 + l15) * 64 + (((kk * 4 + quad) ^ sw) << 3));
#pragma unroll
      for (int j = 0; j < 4; ++j)
        b[j].i = *(const int4*)(Bs + (wc + j * 16 + l15) * 64 + (((kk * 4 + quad) ^ sw) << 3));
#pragma unroll
      for (int i = 0; i < 4; ++i)
#pragma unroll
        for (int j = 0; j < 4; ++j)
          acc[i][j] = mfma16(a[i], b[j], acc[i][j]);
    }
  }
  float bj[4];
#pragma unroll
  for (int j = 0; j < 4; ++j) bj[j] = bias[n0 + wc + j * 16 + l15];

  // routing (block-uniform: n0 block-uniform, wc<128 so grp = n0>>7)
  int hidx = (int)(n0 / 384);
  int rsel = (int)(n0 - hidx * 384) >> 7;  // 0=Q 1=K 2=V

  if (MODE == 1 && rsel == 2) {
    // ---- V^T direct write through LDS, tiled-coalesced ----
    __syncthreads();  // all waves done reading As/Bs (SM reused as [128][130])
#pragma unroll
    for (int i = 0; i < 4; ++i)
#pragma unroll
      for (int rr2 = 0; rr2 < 4; ++rr2) {
        int m = wr + i * 16 + quad * 4 + rr2;  // s within tile
#pragma unroll
        for (int j = 0; j < 4; ++j)
          SM[(wc + j * 16 + l15) * 130 + m] = f2b(acc[i][j][rr2] + bj[j]);
      }
    __syncthreads();
    int bidx = (int)(m0 >> 11);
    int stile = (int)((m0 & 2047) >> 7);
    u16* vtile = vt + (long)(bidx * 16 + hidx) * 262144 + stile * 16384;
    const unsigned* sm32 = (const unsigned*)SM;
#pragma unroll
    for (int it = 0; it < 8; ++it) {
      int ci = it * 256 + t;               // [0,2048)
      int d = ci >> 4, sb = (ci & 15) * 8; // lanes: consecutive s -> coalesced
      int base = (d * 130 + sb) >> 1;      // dword-aligned (130,sb even)
      *(int4*)(vtile + d * 128 + sb) =
          make_int4(sm32[base], sm32[base + 1], sm32[base + 2], sm32[base + 3]);
    }
    return;
  }

  u16* route = (MODE == 1) ? (rsel == 0 ? qb : kbv) : nullptr;

#pragma unroll
  for (int i = 0; i < 4; ++i) {
#pragma unroll
    for (int rr2 = 0; rr2 < 4; ++rr2) {
      long row = m0 + wr + i * 16 + quad * 4 + rr2;
#pragma unroll
      for (int j = 0; j < 4; ++j) {
        float v = acc[i][j][rr2] + bj[j];
        if (MODE == 1) {
          if (rsel == 0) v *= QSCALE;  // pre-scale Q (block-uniform branch)
          int bidx = (int)(row >> 11), s = (int)(row & 2047);
          long obase = ((long)(bidx * 16 + hidx) * 2048 + s) * 128;
          int dh = wc + j * 16 + l15;
          unsigned pb = f2b(v);
          unsigned other = __shfl_xor(pb, 1);
          if (!(l15 & 1))
            ((unsigned*)route)[(obase + dh) >> 1] = pb | (other << 16);
        } else {
          long col = n0 + wc + j * 16 + l15;
          unsigned bits = __float_as_uint(v);
          unsigned other = __shfl_xor(bits, 1);
          if (!(l15 & 1)) {
            uint2 pr; pr.x = bits; pr.y = other;
            *(uint2*)((float*)Cout + row * N + col) = pr;
          }
        }
      }
    }
  }
}

// ---------------- flash attention: 32x32x16, S^T, dbuf + counted vmcnt ----------------
// KVBLK=128: LDS 128KB (1 block/CU either way since grid=256=CU count),
// barrier rounds 32->16, 4 independent St chains (ILP). exp2 via EXP2F builtin
// (R9 post-mortem: raw v_exp_f32 asm breaks trans-op wait-state handling).
// 8 waves/block (512 thr), 256 q-rows/block, 256 main blocks (1/CU).
// XCD/bh-grouping block remap: d0=by*8+bx; bh=(d0&7)+((d0>>6)<<3), jq=(d0>>3)&7
// (bijective on [0,256)); all 8 q-blocks of a bh land on one XCD.
// by in [32,64): Wout-transpose tail blocks, 4 tiles per 512-thread block.
__global__ __launch_bounds__(512, 2) void k_flash(const u16* __restrict__ qb,
                                                  const u16* __restrict__ kb,
                                                  const u16* __restrict__ vt,
                                                  u16* __restrict__ attn,
                                                  const float* __restrict__ Wout,
                                                  u16* __restrict__ woutt) {
  __shared__ __attribute__((aligned(16))) u16 Ks[2][128 * 128];   // [key][dh], chunk-swizzled
  __shared__ __attribute__((aligned(16))) u16 Vts[2][128 * 128];  // [dh][key], chunk-swizzled
  if (blockIdx.y >= 32) {  // fused Wout transpose tail (4 tiles per block)
    int half = threadIdx.x >> 8, tt = threadIdx.x & 255;
    u16 (*Tb)[68] = (u16(*)[68])(&Ks[0][0] + half * 64 * 68);
    int ub = ((blockIdx.y - 32) * 8 + blockIdx.x) * 4 + half * 2;
#pragma unroll
    for (int rep = 0; rep < 2; ++rep) {
      int u = ub + rep;  // [0, 1024) = 32x32 tiles
      transpose_tile(Wout, woutt, 2048, 2048, u & 31, u >> 5, tt, Tb);
      __syncthreads();  // Tb reuse between reps (store reads done)
    }
    return;
  }
  int t = threadIdx.x;
  int lane = t & 63, w = t >> 6, l31 = lane & 31, h = lane >> 5;
  // XCD/bh-grouping remap (bijective; see header comment)
  int d0 = blockIdx.y * 8 + blockIdx.x;        // dispatch index [0,256)
  int bh = (d0 & 7) + ((d0 >> 6) << 3);        // [0,32)
  int jq = (d0 >> 3) & 7;                      // q-tile [0,8)
  int q0 = jq * 256 + w * 32;
  int b = bh >> 4, hd = bh & 15;

  // Q B-frags from contiguous qb: lane holds Q[q0+l31][dht*16 + h*8 + j]
  const u16* qbase = qb + ((long)bh * 2048 + q0 + l31) * 128;
  U128 qf[8];
#pragma unroll
  for (int dht = 0; dht < 8; ++dht)
    qf[dht].i = *(const int4*)(qbase + dht * 16 + h * 8);
  // Drain Q loads so no q-load vmcnt dependency is carried into the loop.
  __syncthreads();

  f32x16 O[4] = {};  // O^T: col=q, rows=dh (4 blocks of 32)
  float ls0 = 0.f, ls1 = 0.f, ls2 = 0.f, ls3 = 0.f;
  const u16* kbh = kb + (long)bh * 2048 * 128;
  long vbase = (long)bh * 262144;  // tiled vt: [bh][stile][d][s%128]

  // Merged per-lane LDS read base (u16 units; K and V^T both row-stride 128):
  //  K:  addr = kb2*4096 + (kinv ^ (dht<<4)),  row = kb2*32+l31
  //  V:  addr = dht*4096 + (kinv ^ (kt<<4)),   row = dht*32+l31
  //  kinv = l31<<7 ^ ((l31&7)<<3) ^ (h<<3); XOR fields disjoint from +4096 terms.
  unsigned kinv = ((unsigned)l31 << 7) ^ (unsigned)(((l31 & 7) << 3) ^ (h << 3));

  // stage one 128-key tile: 8 gll16/thread (4 K chunks + 4 V^T chunks)
  auto stage = [&](int buf, int k0) {
#pragma unroll
    for (int it = 0; it < 4; ++it) {  // K tile: 128 keys x 128 dh
      int ci = it * 512 + t;
      int key = ci >> 4, cp = ci & 15, cl = cp ^ (key & 7);
      gll16(kbh + (long)(k0 + key) * 128 + cl * 8, &Ks[buf][0] + ci * 8);
    }
#pragma unroll
    for (int it = 0; it < 4; ++it) {  // V^T tile: one contiguous 32KB stile
      int ci = it * 512 + t;
      int d = ci >> 4, cp = ci & 15, cl = cp ^ (d & 7);
      gll16(vt + vbase + ((long)(k0 >> 7) << 14) + d * 128 + cl * 8,
            &Vts[buf][0] + ci * 8);
    }
  };

  stage(0, 0);
  int cur = 0;
  for (int k0 = 0; k0 < 2048; k0 += 128) {
    if (k0 + 128 < 2048) {
      stage(cur ^ 1, k0 + 128);                         // prefetch next tile
      asm volatile("s_waitcnt vmcnt(8)" ::: "memory");  // current tile landed
    } else {
      asm volatile("s_waitcnt vmcnt(0)" ::: "memory");  // last tile: drain
    }
    __builtin_amdgcn_s_barrier();
    asm volatile("" ::: "memory");  // fence: no LDS reads hoist above barrier
    const u16* KbT = &Ks[cur][0];
    const u16* VbT = &Vts[cur][0];

    // ---- QK cluster: S^T = K * Q^T (four 32-key blocks, 32 mfma, 4 chains) ----
    f32x16 St0 = {}, St1 = {}, St2 = {}, St3 = {};
    __builtin_amdgcn_s_setprio(1);
#pragma unroll
    for (int dht = 0; dht < 8; ++dht) {
      unsigned ka = kinv ^ (unsigned)(dht << 4);
      U128 k0f, k1f, k2f, k3f;
      k0f.i = *(const int4*)(KbT + ka);
      k1f.i = *(const int4*)(KbT + ka + 4096);
      k2f.i = *(const int4*)(KbT + ka + 8192);
      k3f.i = *(const int4*)(KbT + ka + 12288);
      St0 = mfma32(k0f, qf[dht], St0);
      St1 = mfma32(k1f, qf[dht], St1);
      St2 = mfma32(k2f, qf[dht], St2);
      St3 = mfma32(k3f, qf[dht], St3);
    }
    __builtin_amdgcn_s_setprio(0);

    // PV helper: O[dht] += V^T[dht-block] * pf  (4 reads + 4 mfma), kt in [0,8)
    auto pv = [&](int kt, const U128& pfk) {
#pragma unroll
      for (int dht = 0; dht < 4; ++dht) {
        U128 vf;
        vf.i = *(const int4*)(VbT + dht * 4096 + (kinv ^ (unsigned)(kt << 4)));
        O[dht] = mfma32(vf, pfk, O[dht]);
      }
    };
    // pf builder: pack 8 p-values to bf16 pairs, lane-half exchange in-register
    auto mkpf = [&](const float* p) {
      unsigned w0 = pk2bf(p[0], p[1]);
      unsigned w1 = pk2bf(p[2], p[3]);
      unsigned w2 = pk2bf(p[4], p[5]);
      unsigned w3 = pk2bf(p[6], p[7]);
      plswap(w0, w2);
      plswap(w1, w3);
      U128 r; r.i = make_int4(w0, w1, w2, w3);
      return r;
    };
    // SM helper: exp2 8 values of St into p, 4-way partial sums
#define SM8(St, p, off)                                        \
    {                                                          \
      p[off + 0] = EXP2F(St[off + 0]); ls0 += p[off + 0];      \
      p[off + 1] = EXP2F(St[off + 1]); ls1 += p[off + 1];      \
      p[off + 2] = EXP2F(St[off + 2]); ls2 += p[off + 2];      \
      p[off + 3] = EXP2F(St[off + 3]); ls3 += p[off + 3];      \
      p[off + 4] = EXP2F(St[off + 4]); ls0 += p[off + 4];      \
      p[off + 5] = EXP2F(St[off + 5]); ls1 += p[off + 5];      \
      p[off + 6] = EXP2F(St[off + 6]); ls2 += p[off + 6];      \
      p[off + 7] = EXP2F(St[off + 7]); ls3 += p[off + 7];      \
    }

    // ---- interleaved softmax + PV (8 pv batches over 4 St blocks) ----
    float p0[16], p1[16], p2[16], p3[16];
    SM8(St0, p0, 0) SM8(St0, p0, 8)
    U128 pf0a = mkpf(&p0[0]), pf0b = mkpf(&p0[8]);
    pv(0, pf0a);
    SM8(St1, p1, 0)
    pv(1, pf0b);
    SM8(St1, p1, 8)
    U128 pf1a = mkpf(&p1[0]), pf1b = mkpf(&p1[8]);
    pv(2, pf1a);
    SM8(St2, p2, 0)
    pv(3, pf1b);
    SM8(St2, p2, 8)
    U128 pf2a = mkpf(&p2[0]), pf2b = mkpf(&p2[8]);
    pv(4, pf2a);
    SM8(St3, p3, 0)
    pv(5, pf2b);
    SM8(St3, p3, 8)
    U128 pf3a = mkpf(&p3[0]), pf3b = mkpf(&p3[8]);
    __builtin_amdgcn_s_setprio(1);
    pv(6, pf3a);
    pv(7, pf3b);
    __builtin_amdgcn_s_setprio(0);
#undef SM8

    asm volatile("" ::: "memory");  // fence: all LDS reads done before re-stage
    __builtin_amdgcn_s_barrier();
    cur ^= 1;
  }

  // finalize: l[q] = own + partner half; divide; packed dwordx2 stores
  float lsum = (ls0 + ls1) + (ls2 + ls3);
  float ltot = lsum + __shfl_xor(lsum, 32);
  float inv = 1.f / ltot;
  long orow = (long)b * 2048 + q0 + l31;
  u16* ob = attn + orow * 2048 + hd * 128;
#pragma unroll
  for (int dht = 0; dht < 4; ++dht)
#pragma unroll
    for (int g = 0; g < 4; ++g) {
      int dh = dht * 32 + g * 8 + h * 4;  // rows (reg&3)+8*(reg>>2)+4h, regs 4g..4g+3
      float v0 = O[dht][4 * g + 0] * inv, v1 = O[dht][4 * g + 1] * inv;
      float v2 = O[dht][4 * g + 2] * inv, v3 = O[dht][4 * g + 3] * inv;
      uint2 pkd;
      pkd.x = pk2bf(v0, v1);
      pkd.y = pk2bf(v2, v3);
      *(uint2*)(ob + dh) = pkd;
    }
}

extern "C" void kernel_launch(void* const* d_in, const int* in_sizes, int n_in,
                              void* d_out, int out_size, void* d_ws, size_t ws_size,
                              hipStream_t stream) {
  const float* x    = (const float*)d_in[0];
  const float* Wqkv = (const float*)d_in[1];
  const float* bqkv = (const float*)d_in[2];
  const float* Wout = (const float*)d_in[3];
  const float* bout = (const float*)d_in[4];
  float* out = (float*)d_out;
  char* ws = (char*)d_ws;

  // Workspace overlay (peak 75,497,472 B in ws; d_out = 33.55 MB doubles as scratch):
  //   phase A (k_pre + GEMM1):
  //            xb (bf16 x, 16.78 MB)  -> d_out[0, 16.78M)  [dead after GEMM1]
  //            wqkvt (25.17 MB)       -> ws[0, 25165824)   [dead after GEMM1]
  //            qb  [bh][s][dh]        -> ws[25165824, 41943040)
  //            kb  [bh][s][dh]        -> ws[41943040, 58720256)
  //            vt  [bh][stile][d][s]  -> ws[58720256, 75497472)  (GEMM1 writes directly)
  //   phase B (flash + GEMM2):
  //            woutt (8.39 MB)        -> ws[0, 8388608)    (flash tail blocks; wqkvt dead)
  //            attnb (16.78 MB)       -> ws[8388608, 25165824)
  //   qb/kb/vt dead before GEMM2 writes d_out; d_out fully free from flash on.
  if (ws_size < 75497472u) return;  // diagnostic guard: fail cleanly, not fault

  u16* xb    = (u16*)d_out;
  u16* wqkvt = (u16*)(ws);
  u16* qbuf  = (u16*)(ws + 25165824);
  u16* kbuf  = (u16*)(ws + 41943040);
  u16* vtb   = (u16*)(ws + 58720256);
  u16* woutt = (u16*)(ws);             // after GEMM1 (wqkvt dead)
  u16* attnb = (u16*)(ws + 8388608);   // after GEMM1

  // 4 launches: pre(conv+WqkvT) -> GEMM1(+V^T epi) -> flash(+WoutT) -> GEMM2
  k_pre<<<11264, 256, 0, stream>>>(x, xb, Wqkv, wqkvt);
  k_gemm_bt<1><<<dim3(48, 32), 256, 0, stream>>>(xb, wqkvt, bqkv, nullptr,
                                                 qbuf, kbuf, vtb, 0, 4096, 6144, 2048);
  k_flash<<<dim3(8, 64), 512, 0, stream>>>(qbuf, kbuf, vtb, attnb, Wout, woutt);
  k_gemm_bt<0><<<dim3(16, 32), 256, 0, stream>>>(attnb, woutt, bout, out,
                                                 nullptr, nullptr, nullptr, 0, 4096, 2048, 2048);
}